// Round 6
// baseline (94.919 us; speedup 1.0000x reference)
//
#include <hip/hip_runtime.h>
#include <hip/hip_bf16.h>

#define D_IN  2048
#define D_OUT 2048
#define M_TOTAL 8192   // B*S = 4*2048

typedef __attribute__((ext_vector_type(4))) float  f32x4;
typedef __attribute__((ext_vector_type(8))) short  short8;   // 8 bf16 for MFMA A/B frags
typedef __attribute__((ext_vector_type(4))) unsigned short u16x4;

typedef const __attribute__((address_space(1))) void gvoid_t;
typedef __attribute__((address_space(3))) void lvoid_t;

__device__ __forceinline__ unsigned short f2bf_rne(float f) {
    unsigned int u = __builtin_bit_cast(unsigned int, f);
    u = (u + 0x7FFFu + ((u >> 16) & 1u));
    return (unsigned short)(u >> 16);
}

// ---------------------------------------------------------------------------
// Kernel 1: per-block partial sums of |w| in fp64 (deterministic, no atomics)
// ---------------------------------------------------------------------------
__global__ __launch_bounds__(256) void absum_kernel(const float* __restrict__ w,
                                                    double* __restrict__ partials) {
    const int n4 = (D_OUT * D_IN) / 4;          // 1,048,576 float4s
    int tid = blockIdx.x * 256 + threadIdx.x;
    int stride = gridDim.x * 256;
    double s = 0.0;
    for (int i = tid; i < n4; i += stride) {
        float4 v = reinterpret_cast<const float4*>(w)[i];
        s += (double)fabsf(v.x) + (double)fabsf(v.y) +
             (double)fabsf(v.z) + (double)fabsf(v.w);
    }
    for (int off = 32; off; off >>= 1) s += __shfl_xor(s, off, 64);
    __shared__ double ls[4];
    if ((threadIdx.x & 63) == 0) ls[threadIdx.x >> 6] = s;
    __syncthreads();
    if (threadIdx.x == 0)
        partials[blockIdx.x] = ls[0] + ls[1] + ls[2] + ls[3];
}

// ---------------------------------------------------------------------------
// Kernel 2: ternary quantize -> bf16 [D_OUT][D_IN]; finalize folded in
// ---------------------------------------------------------------------------
__global__ __launch_bounds__(256) void quant_kernel(const float* __restrict__ w,
                                                    const double* __restrict__ partials,
                                                    unsigned short* __restrict__ wq) {
    int t = threadIdx.x;
    double s = partials[t] + partials[t + 256] + partials[t + 512] + partials[t + 768];
    for (int off = 32; off; off >>= 1) s += __shfl_xor(s, off, 64);
    __shared__ double ls[4];
    if ((t & 63) == 0) ls[t >> 6] = s;
    __syncthreads();
    double tot = ls[0] + ls[1] + ls[2] + ls[3];
    double inv = 1.0 / (tot / 4194304.0 + 1e-5);

    int i = blockIdx.x * 256 + t;                  // 1M threads, 4 elems each
    float4 v = reinterpret_cast<const float4*>(w)[i];
    u16x4 o;
    #pragma unroll
    for (int j = 0; j < 4; ++j) {
        float wf = (j == 0) ? v.x : (j == 1) ? v.y : (j == 2) ? v.z : v.w;
        double r = rint((double)wf * inv);
        r = fmin(1.0, fmax(-1.0, r));
        float f = (float)r;                         // exactly -1, 0, or 1
        o[j] = (unsigned short)(__builtin_bit_cast(unsigned int, f) >> 16);
    }
    *reinterpret_cast<u16x4*>(&wq[i * 4]) = o;
}

// ---------------------------------------------------------------------------
// Kernel 3: fused LayerNorm (fp32 in) -> bf16 [M][D_IN]
// ---------------------------------------------------------------------------
__global__ __launch_bounds__(256) void ln_kernel(const float* __restrict__ x,
                                                 const float* __restrict__ gamma,
                                                 const float* __restrict__ beta,
                                                 unsigned short* __restrict__ xn) {
    int row = blockIdx.x;
    const float4* xr = reinterpret_cast<const float4*>(x + (size_t)row * D_IN);
    int t = threadIdx.x;
    float4 v0 = xr[t];
    float4 v1 = xr[t + 256];
    float s  = v0.x + v0.y + v0.z + v0.w + v1.x + v1.y + v1.z + v1.w;
    float sq = v0.x*v0.x + v0.y*v0.y + v0.z*v0.z + v0.w*v0.w
             + v1.x*v1.x + v1.y*v1.y + v1.z*v1.z + v1.w*v1.w;
    for (int off = 32; off; off >>= 1) {
        s  += __shfl_xor(s,  off, 64);
        sq += __shfl_xor(sq, off, 64);
    }
    __shared__ float lss[4], lqq[4];
    if ((t & 63) == 0) { lss[t >> 6] = s; lqq[t >> 6] = sq; }
    __syncthreads();
    s  = lss[0] + lss[1] + lss[2] + lss[3];
    sq = lqq[0] + lqq[1] + lqq[2] + lqq[3];
    float mu  = s * (1.0f / D_IN);
    float var = sq * (1.0f / D_IN) - mu * mu;
    float inv = rsqrtf(var + 1e-5f);

    const float4* g4 = reinterpret_cast<const float4*>(gamma);
    const float4* b4 = reinterpret_cast<const float4*>(beta);
    float4 g0 = g4[t], g1 = g4[t + 256];
    float4 b0 = b4[t], b1 = b4[t + 256];

    u16x4 o0, o1;
    o0[0] = f2bf_rne((v0.x - mu) * inv * g0.x + b0.x);
    o0[1] = f2bf_rne((v0.y - mu) * inv * g0.y + b0.y);
    o0[2] = f2bf_rne((v0.z - mu) * inv * g0.z + b0.z);
    o0[3] = f2bf_rne((v0.w - mu) * inv * g0.w + b0.w);
    o1[0] = f2bf_rne((v1.x - mu) * inv * g1.x + b1.x);
    o1[1] = f2bf_rne((v1.y - mu) * inv * g1.y + b1.y);
    o1[2] = f2bf_rne((v1.z - mu) * inv * g1.z + b1.z);
    o1[3] = f2bf_rne((v1.w - mu) * inv * g1.w + b1.w);

    unsigned short* orow = xn + (size_t)row * D_IN;
    *reinterpret_cast<u16x4*>(&orow[t * 4])        = o0;
    *reinterpret_cast<u16x4*>(&orow[1024 + t * 4]) = o1;
}

// ---------------------------------------------------------------------------
// Kernel 4: 256x256-tile 8-wave bf16 MFMA GEMM — R5: TWO barriers per K-tile.
// Read-ahead retained (frags for phase p+1 read at phase p top). Stages
// consolidated: ph1 stages kh1(T+1) [4 loads], ph3 stages kh0(T+2) [4 loads].
// Waits: vmcnt(4) at ph0-end (drains kh1(T), staged T-1.ph1) and ph2-end
// (drains kh0(T+1), staged T-1.ph3); barrier ONLY after these two waits.
// Hazard ledger (verified):
//  WAR: ph1 stage->so+16K/49152: prior kh1(T-1) reads lgkm-complete before
//   T-1.ph3 cluster < T.ph0-end barrier < stage. ph3 stage->sb/sb+32K: kh0(T)
//   last consumed at T.ph1 cluster < T.ph2-end barrier < stage.
//  RAW: ph1-top reads kh1(T): all-wave drain at T.ph0-end vmcnt+barrier.
//   ph3-top reads kh0(T+1): drained at T.ph2-end vmcnt+barrier.
//  Steady: 8 loads in flight; each vmcnt(4) retires exactly the 4 oldest.
// Barrier-free ph1->ph2 and ph3->ph0 stretches let waves stagger => LDS pipe
// and matrix pipe overlap ACROSS waves (the lockstep serialization fix).
// ---------------------------------------------------------------------------
#define BM 256
#define BN 256
#define BKT 64
#define NT (D_IN / BKT)        // 32
#define SLOT_BYTES 65536

__device__ __forceinline__ void stage_quantum(const unsigned short* __restrict__ gbase,
                                              int grow0, int kcol0,
                                              char* smem, int ldsbase, int tid) {
    const int lane = tid & 63;
    const int w    = tid >> 6;
    // pre-swizzled global column: slot_p ^ f(row), f(row)=((row>>1)&3)=(lane>>3)&3 here
    const int colx = (((lane & 3) ^ ((lane >> 3) & 3)) << 3);
    #pragma unroll
    for (int j = 0; j < 2; ++j) {
        const int c = w * 2 + j;                    // 1KB chunk id, 0..15
        const int r = c * 16 + (lane >> 2);         // row within 256
        const unsigned short* g = gbase + (size_t)(grow0 + r) * D_IN + (kcol0 + colx);
        char* l = smem + ldsbase + c * 1024 + lane * 16;   // linear: wave-uniform + lane*16
        __builtin_amdgcn_global_load_lds((gvoid_t*)g, (lvoid_t*)l, 16, 0, 0);
    }
}

__device__ __forceinline__ short8 rdfrag(const char* smem, int off) {
    return *reinterpret_cast<const short8*>(smem + off);
}

template<int W>
__device__ __forceinline__ void vm_wait() {
    if constexpr (W == 4) {
        asm volatile("s_waitcnt vmcnt(4)" ::: "memory");
        __builtin_amdgcn_sched_barrier(0);
    } else if constexpr (W == 0) {
        asm volatile("s_waitcnt vmcnt(0)" ::: "memory");
        __builtin_amdgcn_sched_barrier(0);
    }
    // W == -1: no wait
}

#define MFMA16(ROW, AV, BV)                                                     \
    __builtin_amdgcn_sched_barrier(0);                                          \
    __builtin_amdgcn_s_setprio(1);                                              \
    _Pragma("unroll")                                                           \
    for (int m_ = 0; m_ < 4; ++m_)                                              \
        _Pragma("unroll")                                                       \
        for (int n_ = 0; n_ < 4; ++n_)                                          \
            acc[ROW + m_][n_] = __builtin_amdgcn_mfma_f32_16x16x32_bf16(        \
                AV[m_], BV[n_], acc[ROW + m_][n_], 0, 0, 0);                    \
    __builtin_amdgcn_s_setprio(0);                                              \
    __builtin_amdgcn_sched_barrier(0);

template<bool S1, bool S2, int W0, int W2, bool RD3>
__device__ __forceinline__ void ktile(int T,
        const unsigned short* __restrict__ A, const unsigned short* __restrict__ B,
        int bm, int bn, char* smem, int tid, int aBase, int bBase,
        short8 (&aS0)[4], short8 (&aS1)[4], short8 (&bE)[4], short8 (&bO)[4],
        f32x4 (&acc)[8][4]) {
    const int sb = (T & 1) * SLOT_BYTES;
    const int so = sb ^ SLOT_BYTES;

    // ---- ph0: read A-kh0 m4-7; cluster (m0-3, kh0); vmcnt(4); BARRIER ----
    #pragma unroll
    for (int f = 0; f < 4; ++f) aS1[f] = rdfrag(smem, sb + aBase + 4096 + f * 1024);
    MFMA16(0, aS0, bE)
    vm_wait<W0>();
    __builtin_amdgcn_s_barrier();

    // ---- ph1: read A-kh1 m0-3 + B-kh1; stage kh1(T+1); cluster (m4-7, kh0) ----
    #pragma unroll
    for (int f = 0; f < 4; ++f) aS0[f] = rdfrag(smem, sb + 16384 + aBase + f * 1024);
    #pragma unroll
    for (int f = 0; f < 4; ++f) bO[f]  = rdfrag(smem, sb + 49152 + bBase + f * 1024);
    if (S1) {
        stage_quantum(A, bm, (T + 1) * BKT + 32, smem, so + 16384, tid);
        stage_quantum(B, bn, (T + 1) * BKT + 32, smem, so + 49152, tid);
    }
    MFMA16(4, aS1, bE)
    // no barrier — waves stagger here

    // ---- ph2: read A-kh1 m4-7; cluster (m0-3, kh1); vmcnt(4); BARRIER ----
    #pragma unroll
    for (int f = 0; f < 4; ++f) aS1[f] = rdfrag(smem, sb + 16384 + aBase + 4096 + f * 1024);
    MFMA16(0, aS0, bO)
    vm_wait<W2>();
    __builtin_amdgcn_s_barrier();

    // ---- ph3: read next-tile kh0 frags; stage kh0(T+2); cluster (m4-7, kh1) ----
    if (RD3) {
        #pragma unroll
        for (int f = 0; f < 4; ++f) aS0[f] = rdfrag(smem, so + aBase + f * 1024);
        #pragma unroll
        for (int f = 0; f < 4; ++f) bE[f]  = rdfrag(smem, so + 32768 + bBase + f * 1024);
    }
    if (S2) {
        stage_quantum(A, bm, (T + 2) * BKT, smem, sb, tid);
        stage_quantum(B, bn, (T + 2) * BKT, smem, sb + 32768, tid);
    }
    MFMA16(4, aS1, bO)
    // no barrier — waves stagger into next tile's ph0
}

__global__ __launch_bounds__(512, 2) void gemm256_kernel(const unsigned short* __restrict__ A,
                                                         const unsigned short* __restrict__ B,
                                                         const float* __restrict__ bias,
                                                         float* __restrict__ C) {
    extern __shared__ char smem[];
    const int tid  = threadIdx.x;
    const int lane = tid & 63;
    const int wid  = tid >> 6;
    const int wm   = wid >> 2;           // 0..1
    const int wn   = wid & 3;            // 0..3

    // XCD-aware bijective swizzle (grid=256): each XCD owns 4 contiguous
    // M-panels (4MB A in its private L2)
    const int orig = blockIdx.y * gridDim.x + blockIdx.x;   // 0..255
    const int swz  = (orig & 7) * 32 + (orig >> 3);
    const int bm   = (swz >> 3) * BM;
    const int bn   = (swz & 7) * BN;

    const int lr   = lane & 15;
    // swizzled per-lane ds_read base: row=lr, slot = (lane>>4) ^ ((lr>>1)&3)
    const int rdbase = lr * 64 + ((((lane >> 4) ^ ((lr >> 1) & 3))) << 4);
    const int aBase = wm * 8192 + rdbase;
    const int bBase = wn * 4096 + rdbase;

    f32x4 acc[8][4];
    #pragma unroll
    for (int m = 0; m < 8; ++m)
        #pragma unroll
        for (int n = 0; n < 4; ++n)
            acc[m][n] = (f32x4){0.f, 0.f, 0.f, 0.f};

    short8 aS0[4], aS1[4], bE[4], bO[4];

    // prologue: kh0(0), kh1(0), kh0(1) staged (12 loads); drain kh0(0) ->
    // vmcnt(8); barrier; pre-read ph0(T=0) frags (A-kh0 m0-3, B-kh0).
    stage_quantum(A, bm, 0,  smem, 0,                     tid);
    stage_quantum(B, bn, 0,  smem, 32768,                 tid);
    stage_quantum(A, bm, 32, smem, 16384,                 tid);
    stage_quantum(B, bn, 32, smem, 49152,                 tid);
    stage_quantum(A, bm, 64, smem, SLOT_BYTES,            tid);
    stage_quantum(B, bn, 64, smem, SLOT_BYTES + 32768,    tid);
    asm volatile("s_waitcnt vmcnt(8)" ::: "memory");
    __builtin_amdgcn_sched_barrier(0);
    __builtin_amdgcn_s_barrier();
    #pragma unroll
    for (int f = 0; f < 4; ++f) aS0[f] = rdfrag(smem, aBase + f * 1024);
    #pragma unroll
    for (int f = 0; f < 4; ++f) bE[f]  = rdfrag(smem, 32768 + bBase + f * 1024);
    __builtin_amdgcn_sched_barrier(0);

    for (int T = 0; T < NT - 2; ++T)
        ktile<true, true, 4, 4, true>(T, A, B, bm, bn, smem, tid, aBase, bBase,
                                      aS0, aS1, bE, bO, acc);
    ktile<true,  false, 4,  4, true >(NT - 2, A, B, bm, bn, smem, tid, aBase, bBase,
                                      aS0, aS1, bE, bO, acc);
    ktile<false, false, 0, -1, false>(NT - 1, A, B, bm, bn, smem, tid, aBase, bBase,
                                      aS0, aS1, bE, bO, acc);

    // ---- epilogue: per-wave LDS repack -> dwordx4 stores (256B segments) ----
    // Last tile's reads are all in slot1 (sb=64K+); epilogue uses slot0 area
    // (per-wave private, 4352B each) -> no barrier needed.
    const int EST = 272;                       // row stride bytes (68 dwords, anti-conflict pad)
    char* eb = smem + wid * (16 * EST);        // 4352 B per wave
    const int C0 = bn + wn * 64;
    const int R0 = bm + wm * 128;
    const int rowsub = (lane >> 4) * 4;
    float bv[4];
    #pragma unroll
    for (int n = 0; n < 4; ++n) bv[n] = bias[C0 + n * 16 + lr];

    #pragma unroll
    for (int m = 0; m < 8; ++m) {
        #pragma unroll
        for (int n = 0; n < 4; ++n)
            #pragma unroll
            for (int i = 0; i < 4; ++i)
                *reinterpret_cast<float*>(eb + (rowsub + i) * EST + (n * 16 + lr) * 4)
                    = acc[m][n][i] + bv[n];
        #pragma unroll
        for (int q = 0; q < 4; ++q) {
            const int row = (lane >> 4) + q * 4;
            f32x4 v = *reinterpret_cast<const f32x4*>(eb + row * EST + lr * 16);
            *reinterpret_cast<f32x4*>(&C[(size_t)(R0 + m * 16 + row) * D_OUT + C0 + lr * 4]) = v;
        }
    }
}

// ---------------------------------------------------------------------------
extern "C" void kernel_launch(void* const* d_in, const int* in_sizes, int n_in,
                              void* d_out, int out_size, void* d_ws, size_t ws_size,
                              hipStream_t stream) {
    const float* x     = (const float*)d_in[0];   // [4,2048,2048]
    const float* w     = (const float*)d_in[1];   // [2048,2048]
    const float* bias  = (const float*)d_in[2];   // [2048]
    const float* gamma = (const float*)d_in[3];   // [2048]
    const float* beta  = (const float*)d_in[4];   // [2048]
    float* out = (float*)d_out;

    char* ws = (char*)d_ws;
    double* partials = (double*)ws;                               // 8KB
    unsigned short* wq = (unsigned short*)(ws + 16384);           // 8 MB bf16 [N][K]
    unsigned short* xn = (unsigned short*)(ws + 16384 + 8ull*1024*1024); // 32 MB bf16 [M][K]

    hipFuncSetAttribute(reinterpret_cast<const void*>(gemm256_kernel),
                        hipFuncAttributeMaxDynamicSharedMemorySize, 131072);

    absum_kernel   <<<1024, 256, 0, stream>>>(w, partials);
    quant_kernel   <<<4096, 256, 0, stream>>>(w, partials, wq);
    ln_kernel      <<<M_TOTAL, 256, 0, stream>>>(x, gamma, beta, xn);
    gemm256_kernel <<<dim3(D_OUT / BN, M_TOTAL / BM), 512, 131072, stream>>>(xn, wq, bias, out);
}

// Round 7
// 70.773 us; speedup vs baseline: 1.3412x; 1.3412x over previous
//
#include <hip/hip_runtime.h>
#include <hip/hip_bf16.h>

#define D_IN  2048
#define D_OUT 2048
#define M_TOTAL 8192   // B*S = 4*2048

typedef __attribute__((ext_vector_type(4))) int   i32x4;   // i8 MFMA A/B/C frags
typedef __attribute__((ext_vector_type(4))) float f32x4;

typedef const __attribute__((address_space(1))) void gvoid_t;
typedef __attribute__((address_space(3))) void lvoid_t;

// ---------------------------------------------------------------------------
// Kernel 1: per-block partial sums of |w| in fp64 (deterministic, no atomics)
// ---------------------------------------------------------------------------
__global__ __launch_bounds__(256) void absum_kernel(const float* __restrict__ w,
                                                    double* __restrict__ partials) {
    const int n4 = (D_OUT * D_IN) / 4;          // 1,048,576 float4s
    int tid = blockIdx.x * 256 + threadIdx.x;
    int stride = gridDim.x * 256;
    double s = 0.0;
    for (int i = tid; i < n4; i += stride) {
        float4 v = reinterpret_cast<const float4*>(w)[i];
        s += (double)fabsf(v.x) + (double)fabsf(v.y) +
             (double)fabsf(v.z) + (double)fabsf(v.w);
    }
    for (int off = 32; off; off >>= 1) s += __shfl_xor(s, off, 64);
    __shared__ double ls[4];
    if ((threadIdx.x & 63) == 0) ls[threadIdx.x >> 6] = s;
    __syncthreads();
    if (threadIdx.x == 0)
        partials[blockIdx.x] = ls[0] + ls[1] + ls[2] + ls[3];
}

// ---------------------------------------------------------------------------
// Kernel 2: ternary quantize -> int8 [D_OUT][D_IN] (B^T layout); finalize
// folded in (every block reduces the 1024 partials identically).
// ---------------------------------------------------------------------------
__global__ __launch_bounds__(256) void quant_kernel(const float* __restrict__ w,
                                                    const double* __restrict__ partials,
                                                    char* __restrict__ wq) {
    int t = threadIdx.x;
    double s = partials[t] + partials[t + 256] + partials[t + 512] + partials[t + 768];
    for (int off = 32; off; off >>= 1) s += __shfl_xor(s, off, 64);
    __shared__ double ls[4];
    if ((t & 63) == 0) ls[t >> 6] = s;
    __syncthreads();
    double tot = ls[0] + ls[1] + ls[2] + ls[3];
    double inv = 1.0 / (tot / 4194304.0 + 1e-5);

    int i = blockIdx.x * 256 + t;                  // 1M threads, 4 elems each
    float4 v = reinterpret_cast<const float4*>(w)[i];
    unsigned o = 0;
    #pragma unroll
    for (int j = 0; j < 4; ++j) {
        float wf = (j == 0) ? v.x : (j == 1) ? v.y : (j == 2) ? v.z : v.w;
        double r = rint((double)wf * inv);
        r = fmin(1.0, fmax(-1.0, r));
        int q = (int)r;                             // -1, 0, or 1
        o |= ((unsigned)(unsigned char)(char)q) << (8 * j);
    }
    reinterpret_cast<unsigned*>(wq)[i] = o;
}

// ---------------------------------------------------------------------------
// Kernel 3: fused LayerNorm (fp32 in) -> int8 [M][D_IN] + per-row scale.
// q = rint(xn * 127/rowmax); s_row = rowmax/127 (max-reduce is exact/determ.)
// ---------------------------------------------------------------------------
__device__ __forceinline__ unsigned pk4(float a, float b, float c, float d, float is) {
    int q0 = (int)rintf(a * is); q0 = min(127, max(-127, q0));
    int q1 = (int)rintf(b * is); q1 = min(127, max(-127, q1));
    int q2 = (int)rintf(c * is); q2 = min(127, max(-127, q2));
    int q3 = (int)rintf(d * is); q3 = min(127, max(-127, q3));
    return  (unsigned)(unsigned char)(char)q0        |
           ((unsigned)(unsigned char)(char)q1 << 8)  |
           ((unsigned)(unsigned char)(char)q2 << 16) |
           ((unsigned)(unsigned char)(char)q3 << 24);
}

__global__ __launch_bounds__(256) void ln_kernel(const float* __restrict__ x,
                                                 const float* __restrict__ gamma,
                                                 const float* __restrict__ beta,
                                                 char* __restrict__ xn,
                                                 float* __restrict__ s_row) {
    int row = blockIdx.x;
    const float4* xr = reinterpret_cast<const float4*>(x + (size_t)row * D_IN);
    int t = threadIdx.x;
    float4 v0 = xr[t];
    float4 v1 = xr[t + 256];
    float s  = v0.x + v0.y + v0.z + v0.w + v1.x + v1.y + v1.z + v1.w;
    float sq = v0.x*v0.x + v0.y*v0.y + v0.z*v0.z + v0.w*v0.w
             + v1.x*v1.x + v1.y*v1.y + v1.z*v1.z + v1.w*v1.w;
    for (int off = 32; off; off >>= 1) {
        s  += __shfl_xor(s,  off, 64);
        sq += __shfl_xor(sq, off, 64);
    }
    __shared__ float lss[4], lqq[4], lmx[4];
    if ((t & 63) == 0) { lss[t >> 6] = s; lqq[t >> 6] = sq; }
    __syncthreads();
    s  = lss[0] + lss[1] + lss[2] + lss[3];
    sq = lqq[0] + lqq[1] + lqq[2] + lqq[3];
    float mu  = s * (1.0f / D_IN);
    float var = sq * (1.0f / D_IN) - mu * mu;
    float inv = rsqrtf(var + 1e-5f);

    const float4* g4 = reinterpret_cast<const float4*>(gamma);
    const float4* b4 = reinterpret_cast<const float4*>(beta);
    float4 g0 = g4[t], g1 = g4[t + 256];
    float4 b0 = b4[t], b1 = b4[t + 256];

    float a0 = (v0.x - mu) * inv * g0.x + b0.x;
    float a1 = (v0.y - mu) * inv * g0.y + b0.y;
    float a2 = (v0.z - mu) * inv * g0.z + b0.z;
    float a3 = (v0.w - mu) * inv * g0.w + b0.w;
    float a4 = (v1.x - mu) * inv * g1.x + b1.x;
    float a5 = (v1.y - mu) * inv * g1.y + b1.y;
    float a6 = (v1.z - mu) * inv * g1.z + b1.z;
    float a7 = (v1.w - mu) * inv * g1.w + b1.w;

    // row absmax (exact max-reduce -> deterministic)
    float mx = fmaxf(fmaxf(fmaxf(fabsf(a0), fabsf(a1)), fmaxf(fabsf(a2), fabsf(a3))),
                     fmaxf(fmaxf(fabsf(a4), fabsf(a5)), fmaxf(fabsf(a6), fabsf(a7))));
    for (int off = 32; off; off >>= 1) mx = fmaxf(mx, __shfl_xor(mx, off, 64));
    if ((t & 63) == 0) lmx[t >> 6] = mx;
    __syncthreads();
    float rowmax = fmaxf(fmaxf(lmx[0], lmx[1]), fmaxf(lmx[2], lmx[3]));

    float is = (rowmax > 0.0f) ? (127.0f / rowmax) : 0.0f;
    char* orow = xn + (size_t)row * D_IN;
    reinterpret_cast<unsigned*>(orow)[t]        = pk4(a0, a1, a2, a3, is);
    reinterpret_cast<unsigned*>(orow + 1024)[t] = pk4(a4, a5, a6, a7, is);
    if (t == 0) s_row[row] = rowmax * (1.0f / 127.0f);
}

// ---------------------------------------------------------------------------
// Kernel 4: 256x256-tile 8-wave INT8 MFMA GEMM (mfma_i32_16x16x64_i8, 2x bf16
// rate). C[m][n] = s_row[m] * (sum_k qx[m][k]*wq[n][k]) + bias[n].
// LDS: 4-slot ring, 32KB/slot (A 16KB @ s*16K, B 16KB @ 64K + s*16K) = 128KB.
// Per K-tile (BK=64 = full MFMA K): 2 phases, 2 barriers, 1 vmcnt(4),
// 12 ds_read_b128/wave, 4 global_load_lds/thread, 32 MFMA/wave.
//   ph0: read A[s] m4-7 | MFMA16(m0-3) | vmcnt(4) | barrier
//   ph1: read-ahead A[s+1] m0-3 + B[s+1] | stage {A,B}(T+3)->slot(T+3)%4 |
//        MFMA16(m4-7) | barrier
// Ledger: tile T+1 data staged at T-2.ph1, drained by T.ph0 vmcnt(4)+barrier
//   (span 3 phases ~2000cy >> HBM 900cy); slot (T+3)%4's last reads consumed
//   by T-1.ph1 cluster (lgkm-forced) -> 2 barriers before T.ph1's stage. WAR ok.
// Bank swizzle (both-sides): phys_kg = kg ^ (row&3); staged via pre-swizzled
//   global col (gload_lds dest linear), read via swizzled ds addr. Half-wave
//   slot occupancy uniform 4/16B-slot -> conflict-free b128.
// ---------------------------------------------------------------------------
#define BM 256
#define BN 256
#define NT (D_IN / 64)         // 32 K-tiles

__device__ __forceinline__ void stage_quantum(const char* __restrict__ gbase,
                                              int grow0, int kcol0,
                                              char* smem, int ldsbase, int tid) {
    const int lane = tid & 63;
    const int w    = tid >> 6;
    // inverse-swizzled global k-group: logical kg = phys(l&3) ^ (row&3)=((l>>2)&3)
    const int colx = (((lane & 3) ^ ((lane >> 2) & 3)) << 4);   // bytes
    #pragma unroll
    for (int j = 0; j < 2; ++j) {
        const int c = w * 2 + j;                    // 1KB chunk id, 0..15 (16 rows each)
        const int r = c * 16 + (lane >> 2);         // row within 256
        const char* g = gbase + (size_t)(grow0 + r) * D_IN + kcol0 + colx;
        char* l = smem + ldsbase + c * 1024 + lane * 16;   // linear dest
        __builtin_amdgcn_global_load_lds((gvoid_t*)g, (lvoid_t*)l, 16, 0, 0);
    }
}

__device__ __forceinline__ i32x4 rdfrag(const char* smem, int off) {
    return *reinterpret_cast<const i32x4*>(smem + off);
}

template<int W>
__device__ __forceinline__ void vm_wait() {
    if constexpr (W == 4) {
        asm volatile("s_waitcnt vmcnt(4)" ::: "memory");
        __builtin_amdgcn_sched_barrier(0);
    } else if constexpr (W == 0) {
        asm volatile("s_waitcnt vmcnt(0)" ::: "memory");
        __builtin_amdgcn_sched_barrier(0);
    }
    // W == -1: no wait
}

#define MFMA16(ROW, AV, BV)                                                     \
    __builtin_amdgcn_sched_barrier(0);                                          \
    __builtin_amdgcn_s_setprio(1);                                              \
    _Pragma("unroll")                                                           \
    for (int m_ = 0; m_ < 4; ++m_)                                              \
        _Pragma("unroll")                                                       \
        for (int n_ = 0; n_ < 4; ++n_)                                          \
            acc[ROW + m_][n_] = __builtin_amdgcn_mfma_i32_16x16x64_i8(          \
                AV[m_], BV[n_], acc[ROW + m_][n_], 0, 0, 0);                    \
    __builtin_amdgcn_s_setprio(0);                                              \
    __builtin_amdgcn_sched_barrier(0);

template<int W, bool S, bool RD>
__device__ __forceinline__ void ktile(int T,
        const char* __restrict__ A, const char* __restrict__ B,
        int bm, int bn, char* smem, int tid, int aBase, int bBase,
        i32x4 (&aS0)[4], i32x4 (&aS1)[4], i32x4 (&bCur)[4], i32x4 (&bNxt)[4],
        i32x4 (&acc)[8][4]) {
    const int sA  = ((T & 3) << 14);
    const int sAn = (((T + 1) & 3) << 14);

    // ---- ph0 ----
    #pragma unroll
    for (int f = 0; f < 4; ++f) aS1[f] = rdfrag(smem, sA + aBase + 4096 + f * 1024);
    MFMA16(0, aS0, bCur)
    vm_wait<W>();
    __builtin_amdgcn_s_barrier();

    // ---- ph1 ----
    if (RD) {
        #pragma unroll
        for (int f = 0; f < 4; ++f) aS0[f]  = rdfrag(smem, sAn + aBase + f * 1024);
        #pragma unroll
        for (int f = 0; f < 4; ++f) bNxt[f] = rdfrag(smem, 65536 + sAn + bBase + f * 1024);
    }
    if (S) {
        const int s3 = (((T + 3) & 3) << 14);
        stage_quantum(A, bm, (T + 3) * 64, smem, s3,         tid);
        stage_quantum(B, bn, (T + 3) * 64, smem, 65536 + s3, tid);
    }
    MFMA16(4, aS1, bCur)
    __builtin_amdgcn_s_barrier();
}

__global__ __launch_bounds__(512, 2) void gemm256_kernel(const char* __restrict__ A,
                                                         const char* __restrict__ B,
                                                         const float* __restrict__ bias,
                                                         const float* __restrict__ s_row,
                                                         float* __restrict__ C) {
    extern __shared__ char smem[];
    const int tid  = threadIdx.x;
    const int lane = tid & 63;
    const int wid  = tid >> 6;
    const int wm   = wid >> 2;           // 0..1
    const int wn   = wid & 3;            // 0..3

    // XCD-aware bijective swizzle (grid=256): each XCD owns 4 contiguous
    // M-panels (L2-resident A)
    const int orig = blockIdx.y * gridDim.x + blockIdx.x;   // 0..255
    const int swz  = (orig & 7) * 32 + (orig >> 3);
    const int bm   = (swz >> 3) * BM;
    const int bn   = (swz & 7) * BN;

    const int lr   = lane & 15;
    // swizzled ds_read base: row=lr (row&3 = lr&3), phys kg = (lane>>4)^(lr&3)
    const int rdbase = lr * 64 + ((((lane >> 4) ^ (lr & 3))) << 4);
    const int aBase = wm * 8192 + rdbase;     // wm*128 rows * 64B
    const int bBase = wn * 4096 + rdbase;     // wn*64 rows * 64B

    i32x4 acc[8][4];
    #pragma unroll
    for (int m = 0; m < 8; ++m)
        #pragma unroll
        for (int n = 0; n < 4; ++n)
            acc[m][n] = (i32x4){0, 0, 0, 0};

    i32x4 aS0[4], aS1[4], bE[4], bO[4];

    // prologue: stage tiles 0,1,2 (12 loads/thread); drain tile0 -> vmcnt(8);
    // barrier; pre-read ph0(T=0) frags.
    stage_quantum(A, bm, 0,   smem, 0,             tid);
    stage_quantum(B, bn, 0,   smem, 65536,         tid);
    stage_quantum(A, bm, 64,  smem, 16384,         tid);
    stage_quantum(B, bn, 64,  smem, 65536 + 16384, tid);
    stage_quantum(A, bm, 128, smem, 32768,         tid);
    stage_quantum(B, bn, 128, smem, 65536 + 32768, tid);
    asm volatile("s_waitcnt vmcnt(8)" ::: "memory");
    __builtin_amdgcn_sched_barrier(0);
    __builtin_amdgcn_s_barrier();
    #pragma unroll
    for (int f = 0; f < 4; ++f) aS0[f] = rdfrag(smem, aBase + f * 1024);
    #pragma unroll
    for (int f = 0; f < 4; ++f) bE[f]  = rdfrag(smem, 65536 + bBase + f * 1024);
    __builtin_amdgcn_sched_barrier(0);

    // even tiles use bE as current, odd tiles bO. Stage while T+3 <= 31.
    for (int T = 0; T < 28; T += 2) {
        ktile<4, true, true>(T,     A, B, bm, bn, smem, tid, aBase, bBase, aS0, aS1, bE, bO, acc);
        ktile<4, true, true>(T + 1, A, B, bm, bn, smem, tid, aBase, bBase, aS0, aS1, bO, bE, acc);
    }
    ktile<4,  true,  true >(28, A, B, bm, bn, smem, tid, aBase, bBase, aS0, aS1, bE, bO, acc);
    ktile<4,  false, true >(29, A, B, bm, bn, smem, tid, aBase, bBase, aS0, aS1, bO, bE, acc);
    ktile<0,  false, true >(30, A, B, bm, bn, smem, tid, aBase, bBase, aS0, aS1, bE, bO, acc);
    ktile<-1, false, false>(31, A, B, bm, bn, smem, tid, aBase, bBase, aS0, aS1, bO, bE, acc);

    // ---- epilogue: out = s_row[row]*acc + bias[col]; LDS repack -> dwordx4 ----
    // K-loop ds_reads all consumed (lgkm-forced before last cluster < final
    // barrier); repack regions are per-wave private.
    const int EST = 272;                       // row stride bytes (anti-conflict pad)
    char* eb = smem + wid * (16 * EST);        // 4352 B per wave
    const int C0 = bn + wn * 64;
    const int R0 = bm + wm * 128;
    const int rowsub = (lane >> 4) * 4;
    float bv[4];
    #pragma unroll
    for (int n = 0; n < 4; ++n) bv[n] = bias[C0 + n * 16 + lr];

    #pragma unroll
    for (int m = 0; m < 8; ++m) {
        float sr[4];
        #pragma unroll
        for (int i = 0; i < 4; ++i) sr[i] = s_row[R0 + m * 16 + rowsub + i];
        #pragma unroll
        for (int n = 0; n < 4; ++n)
            #pragma unroll
            for (int i = 0; i < 4; ++i)
                *reinterpret_cast<float*>(eb + (rowsub + i) * EST + (n * 16 + lr) * 4)
                    = (float)acc[m][n][i] * sr[i] + bv[n];
        #pragma unroll
        for (int q = 0; q < 4; ++q) {
            const int row = (lane >> 4) + q * 4;
            f32x4 v = *reinterpret_cast<const f32x4*>(eb + row * EST + lr * 16);
            *reinterpret_cast<f32x4*>(&C[(size_t)(R0 + m * 16 + row) * D_OUT + C0 + lr * 4]) = v;
        }
    }
}

// ---------------------------------------------------------------------------
extern "C" void kernel_launch(void* const* d_in, const int* in_sizes, int n_in,
                              void* d_out, int out_size, void* d_ws, size_t ws_size,
                              hipStream_t stream) {
    const float* x     = (const float*)d_in[0];   // [4,2048,2048]
    const float* w     = (const float*)d_in[1];   // [2048,2048]
    const float* bias  = (const float*)d_in[2];   // [2048]
    const float* gamma = (const float*)d_in[3];   // [2048]
    const float* beta  = (const float*)d_in[4];   // [2048]
    float* out = (float*)d_out;

    char* ws = (char*)d_ws;
    double* partials = (double*)ws;                         // 8KB
    float*  s_row    = (float*)(ws + 8192);                 // 32KB (8192 rows)
    char*   wq       = ws + 65536;                          // 4MB  i8 [N][K]
    char*   xn       = ws + 65536 + 4ull * 1024 * 1024;     // 16MB i8 [M][K]

    hipFuncSetAttribute(reinterpret_cast<const void*>(gemm256_kernel),
                        hipFuncAttributeMaxDynamicSharedMemorySize, 131072);

    absum_kernel   <<<1024, 256, 0, stream>>>(w, partials);
    quant_kernel   <<<4096, 256, 0, stream>>>(w, partials, wq);
    ln_kernel      <<<M_TOTAL, 256, 0, stream>>>(x, gamma, beta, xn, s_row);
    gemm256_kernel <<<dim3(D_OUT / BN, M_TOTAL / BM), 512, 131072, stream>>>(xn, wq, bias, s_row, out);
}

// Round 8
// 70.000 us; speedup vs baseline: 1.3560x; 1.0110x over previous
//
#include <hip/hip_runtime.h>
#include <hip/hip_bf16.h>

#define D_IN  2048
#define D_OUT 2048
#define M_TOTAL 8192   // B*S = 4*2048

typedef __attribute__((ext_vector_type(4))) int   i32x4;   // i8 MFMA A/B/C frags
typedef __attribute__((ext_vector_type(4))) float f32x4;

typedef const __attribute__((address_space(1))) void gvoid_t;
typedef __attribute__((address_space(3))) void lvoid_t;

// ---------------------------------------------------------------------------
// Kernel 1: per-block partial sums of |w| in fp64 (deterministic, no atomics)
// ---------------------------------------------------------------------------
__global__ __launch_bounds__(256) void absum_kernel(const float* __restrict__ w,
                                                    double* __restrict__ partials) {
    const int n4 = (D_OUT * D_IN) / 4;          // 1,048,576 float4s
    int tid = blockIdx.x * 256 + threadIdx.x;
    int stride = gridDim.x * 256;
    double s = 0.0;
    for (int i = tid; i < n4; i += stride) {
        float4 v = reinterpret_cast<const float4*>(w)[i];
        s += (double)fabsf(v.x) + (double)fabsf(v.y) +
             (double)fabsf(v.z) + (double)fabsf(v.w);
    }
    for (int off = 32; off; off >>= 1) s += __shfl_xor(s, off, 64);
    __shared__ double ls[4];
    if ((threadIdx.x & 63) == 0) ls[threadIdx.x >> 6] = s;
    __syncthreads();
    if (threadIdx.x == 0)
        partials[blockIdx.x] = ls[0] + ls[1] + ls[2] + ls[3];
}

// ---------------------------------------------------------------------------
// Kernel 2: ternary quantize -> int8 [D_OUT][D_IN] (B^T layout); finalize
// folded in (every block reduces the 1024 partials identically).
// ---------------------------------------------------------------------------
__global__ __launch_bounds__(256) void quant_kernel(const float* __restrict__ w,
                                                    const double* __restrict__ partials,
                                                    char* __restrict__ wq) {
    int t = threadIdx.x;
    double s = partials[t] + partials[t + 256] + partials[t + 512] + partials[t + 768];
    for (int off = 32; off; off >>= 1) s += __shfl_xor(s, off, 64);
    __shared__ double ls[4];
    if ((t & 63) == 0) ls[t >> 6] = s;
    __syncthreads();
    double tot = ls[0] + ls[1] + ls[2] + ls[3];
    double inv = 1.0 / (tot / 4194304.0 + 1e-5);

    int i = blockIdx.x * 256 + t;                  // 1M threads, 4 elems each
    float4 v = reinterpret_cast<const float4*>(w)[i];
    unsigned o = 0;
    #pragma unroll
    for (int j = 0; j < 4; ++j) {
        float wf = (j == 0) ? v.x : (j == 1) ? v.y : (j == 2) ? v.z : v.w;
        double r = rint((double)wf * inv);
        r = fmin(1.0, fmax(-1.0, r));
        int q = (int)r;                             // -1, 0, or 1
        o |= ((unsigned)(unsigned char)(char)q) << (8 * j);
    }
    reinterpret_cast<unsigned*>(wq)[i] = o;
}

// ---------------------------------------------------------------------------
// Kernel 3: fused LayerNorm (fp32 in) -> int8 [M][D_IN] + per-row scale.
// q = rint(xn * 127/rowmax); s_row = rowmax/127 (max-reduce is exact/determ.)
// ---------------------------------------------------------------------------
__device__ __forceinline__ unsigned pk4(float a, float b, float c, float d, float is) {
    int q0 = (int)rintf(a * is); q0 = min(127, max(-127, q0));
    int q1 = (int)rintf(b * is); q1 = min(127, max(-127, q1));
    int q2 = (int)rintf(c * is); q2 = min(127, max(-127, q2));
    int q3 = (int)rintf(d * is); q3 = min(127, max(-127, q3));
    return  (unsigned)(unsigned char)(char)q0        |
           ((unsigned)(unsigned char)(char)q1 << 8)  |
           ((unsigned)(unsigned char)(char)q2 << 16) |
           ((unsigned)(unsigned char)(char)q3 << 24);
}

__global__ __launch_bounds__(256) void ln_kernel(const float* __restrict__ x,
                                                 const float* __restrict__ gamma,
                                                 const float* __restrict__ beta,
                                                 char* __restrict__ xn,
                                                 float* __restrict__ s_row) {
    int row = blockIdx.x;
    const float4* xr = reinterpret_cast<const float4*>(x + (size_t)row * D_IN);
    int t = threadIdx.x;
    float4 v0 = xr[t];
    float4 v1 = xr[t + 256];
    float s  = v0.x + v0.y + v0.z + v0.w + v1.x + v1.y + v1.z + v1.w;
    float sq = v0.x*v0.x + v0.y*v0.y + v0.z*v0.z + v0.w*v0.w
             + v1.x*v1.x + v1.y*v1.y + v1.z*v1.z + v1.w*v1.w;
    for (int off = 32; off; off >>= 1) {
        s  += __shfl_xor(s,  off, 64);
        sq += __shfl_xor(sq, off, 64);
    }
    __shared__ float lss[4], lqq[4], lmx[4];
    if ((t & 63) == 0) { lss[t >> 6] = s; lqq[t >> 6] = sq; }
    __syncthreads();
    s  = lss[0] + lss[1] + lss[2] + lss[3];
    sq = lqq[0] + lqq[1] + lqq[2] + lqq[3];
    float mu  = s * (1.0f / D_IN);
    float var = sq * (1.0f / D_IN) - mu * mu;
    float inv = rsqrtf(var + 1e-5f);

    const float4* g4 = reinterpret_cast<const float4*>(gamma);
    const float4* b4 = reinterpret_cast<const float4*>(beta);
    float4 g0 = g4[t], g1 = g4[t + 256];
    float4 b0 = b4[t], b1 = b4[t + 256];

    float a0 = (v0.x - mu) * inv * g0.x + b0.x;
    float a1 = (v0.y - mu) * inv * g0.y + b0.y;
    float a2 = (v0.z - mu) * inv * g0.z + b0.z;
    float a3 = (v0.w - mu) * inv * g0.w + b0.w;
    float a4 = (v1.x - mu) * inv * g1.x + b1.x;
    float a5 = (v1.y - mu) * inv * g1.y + b1.y;
    float a6 = (v1.z - mu) * inv * g1.z + b1.z;
    float a7 = (v1.w - mu) * inv * g1.w + b1.w;

    // row absmax (exact max-reduce -> deterministic)
    float mx = fmaxf(fmaxf(fmaxf(fabsf(a0), fabsf(a1)), fmaxf(fabsf(a2), fabsf(a3))),
                     fmaxf(fmaxf(fabsf(a4), fabsf(a5)), fmaxf(fabsf(a6), fabsf(a7))));
    for (int off = 32; off; off >>= 1) mx = fmaxf(mx, __shfl_xor(mx, off, 64));
    if ((t & 63) == 0) lmx[t >> 6] = mx;
    __syncthreads();
    float rowmax = fmaxf(fmaxf(lmx[0], lmx[1]), fmaxf(lmx[2], lmx[3]));

    float is = (rowmax > 0.0f) ? (127.0f / rowmax) : 0.0f;
    char* orow = xn + (size_t)row * D_IN;
    reinterpret_cast<unsigned*>(orow)[t]        = pk4(a0, a1, a2, a3, is);
    reinterpret_cast<unsigned*>(orow + 1024)[t] = pk4(a4, a5, a6, a7, is);
    if (t == 0) s_row[row] = rowmax * (1.0f / 127.0f);
}

// ---------------------------------------------------------------------------
// Kernel 4: 256x256-tile 8-wave INT8 MFMA GEMM (mfma_i32_16x16x64_i8).
// R7 fix: restore the R2-proven bank swizzle geometry. Row stride is 64B in
// both layouts; the conflict-free involution is f(row) = (row>>1)&3 (spreads
// lanes over 8 distinct 4-dword windows, 2-way = free), NOT row&3 (4 windows,
// 4-way conflict -> the 3.4M conflicts measured in R6).
//   stage: phys slot = lane&3 at row lane>>2; logical kg = phys ^ ((row>>1)&3)
//          -> colx = ((lane&3) ^ ((lane>>3)&3)) << 4
//   read:  phys = (lane>>4) ^ ((lr>>1)&3)
// Everything else identical to R6 (schedule, ring, waits, epilogue).
// ---------------------------------------------------------------------------
#define BM 256
#define BN 256
#define NT (D_IN / 64)         // 32 K-tiles

__device__ __forceinline__ void stage_quantum(const char* __restrict__ gbase,
                                              int grow0, int kcol0,
                                              char* smem, int ldsbase, int tid) {
    const int lane = tid & 63;
    const int w    = tid >> 6;
    // inverse-swizzled global k-group: logical kg = phys(lane&3) ^ ((row>>1)&3),
    // row = lane>>2 -> (row>>1)&3 = (lane>>3)&3
    const int colx = (((lane & 3) ^ ((lane >> 3) & 3)) << 4);   // bytes
    #pragma unroll
    for (int j = 0; j < 2; ++j) {
        const int c = w * 2 + j;                    // 1KB chunk id, 0..15 (16 rows each)
        const int r = c * 16 + (lane >> 2);         // row within 256
        const char* g = gbase + (size_t)(grow0 + r) * D_IN + kcol0 + colx;
        char* l = smem + ldsbase + c * 1024 + lane * 16;   // linear dest
        __builtin_amdgcn_global_load_lds((gvoid_t*)g, (lvoid_t*)l, 16, 0, 0);
    }
}

__device__ __forceinline__ i32x4 rdfrag(const char* smem, int off) {
    return *reinterpret_cast<const i32x4*>(smem + off);
}

template<int W>
__device__ __forceinline__ void vm_wait() {
    if constexpr (W == 4) {
        asm volatile("s_waitcnt vmcnt(4)" ::: "memory");
        __builtin_amdgcn_sched_barrier(0);
    } else if constexpr (W == 0) {
        asm volatile("s_waitcnt vmcnt(0)" ::: "memory");
        __builtin_amdgcn_sched_barrier(0);
    }
    // W == -1: no wait
}

#define MFMA16(ROW, AV, BV)                                                     \
    __builtin_amdgcn_sched_barrier(0);                                          \
    __builtin_amdgcn_s_setprio(1);                                              \
    _Pragma("unroll")                                                           \
    for (int m_ = 0; m_ < 4; ++m_)                                              \
        _Pragma("unroll")                                                       \
        for (int n_ = 0; n_ < 4; ++n_)                                          \
            acc[ROW + m_][n_] = __builtin_amdgcn_mfma_i32_16x16x64_i8(          \
                AV[m_], BV[n_], acc[ROW + m_][n_], 0, 0, 0);                    \
    __builtin_amdgcn_s_setprio(0);                                              \
    __builtin_amdgcn_sched_barrier(0);

template<int W, bool S, bool RD>
__device__ __forceinline__ void ktile(int T,
        const char* __restrict__ A, const char* __restrict__ B,
        int bm, int bn, char* smem, int tid, int aBase, int bBase,
        i32x4 (&aS0)[4], i32x4 (&aS1)[4], i32x4 (&bCur)[4], i32x4 (&bNxt)[4],
        i32x4 (&acc)[8][4]) {
    const int sA  = ((T & 3) << 14);
    const int sAn = (((T + 1) & 3) << 14);

    // ---- ph0 ----
    #pragma unroll
    for (int f = 0; f < 4; ++f) aS1[f] = rdfrag(smem, sA + aBase + 4096 + f * 1024);
    MFMA16(0, aS0, bCur)
    vm_wait<W>();
    __builtin_amdgcn_s_barrier();

    // ---- ph1 ----
    if (RD) {
        #pragma unroll
        for (int f = 0; f < 4; ++f) aS0[f]  = rdfrag(smem, sAn + aBase + f * 1024);
        #pragma unroll
        for (int f = 0; f < 4; ++f) bNxt[f] = rdfrag(smem, 65536 + sAn + bBase + f * 1024);
    }
    if (S) {
        const int s3 = (((T + 3) & 3) << 14);
        stage_quantum(A, bm, (T + 3) * 64, smem, s3,         tid);
        stage_quantum(B, bn, (T + 3) * 64, smem, 65536 + s3, tid);
    }
    MFMA16(4, aS1, bCur)
    __builtin_amdgcn_s_barrier();
}

__global__ __launch_bounds__(512, 2) void gemm256_kernel(const char* __restrict__ A,
                                                         const char* __restrict__ B,
                                                         const float* __restrict__ bias,
                                                         const float* __restrict__ s_row,
                                                         float* __restrict__ C) {
    extern __shared__ char smem[];
    const int tid  = threadIdx.x;
    const int lane = tid & 63;
    const int wid  = tid >> 6;
    const int wm   = wid >> 2;           // 0..1
    const int wn   = wid & 3;            // 0..3

    // XCD-aware bijective swizzle (grid=256): each XCD owns 4 contiguous
    // M-panels (L2-resident A)
    const int orig = blockIdx.y * gridDim.x + blockIdx.x;   // 0..255
    const int swz  = (orig & 7) * 32 + (orig >> 3);
    const int bm   = (swz >> 3) * BM;
    const int bn   = (swz & 7) * BN;

    const int lr   = lane & 15;
    // conflict-free swizzled ds_read base: phys kg = (lane>>4) ^ ((lr>>1)&3)
    const int rdbase = lr * 64 + ((((lane >> 4) ^ ((lr >> 1) & 3))) << 4);
    const int aBase = wm * 8192 + rdbase;     // wm*128 rows * 64B
    const int bBase = wn * 4096 + rdbase;     // wn*64 rows * 64B

    i32x4 acc[8][4];
    #pragma unroll
    for (int m = 0; m < 8; ++m)
        #pragma unroll
        for (int n = 0; n < 4; ++n)
            acc[m][n] = (i32x4){0, 0, 0, 0};

    i32x4 aS0[4], aS1[4], bE[4], bO[4];

    // prologue: stage tiles 0,1,2 (12 loads/thread); drain tile0 -> vmcnt(8);
    // barrier; pre-read ph0(T=0) frags.
    stage_quantum(A, bm, 0,   smem, 0,             tid);
    stage_quantum(B, bn, 0,   smem, 65536,         tid);
    stage_quantum(A, bm, 64,  smem, 16384,         tid);
    stage_quantum(B, bn, 64,  smem, 65536 + 16384, tid);
    stage_quantum(A, bm, 128, smem, 32768,         tid);
    stage_quantum(B, bn, 128, smem, 65536 + 32768, tid);
    asm volatile("s_waitcnt vmcnt(8)" ::: "memory");
    __builtin_amdgcn_sched_barrier(0);
    __builtin_amdgcn_s_barrier();
    #pragma unroll
    for (int f = 0; f < 4; ++f) aS0[f] = rdfrag(smem, aBase + f * 1024);
    #pragma unroll
    for (int f = 0; f < 4; ++f) bE[f]  = rdfrag(smem, 65536 + bBase + f * 1024);
    __builtin_amdgcn_sched_barrier(0);

    // even tiles use bE as current, odd tiles bO. Stage while T+3 <= 31.
    for (int T = 0; T < 28; T += 2) {
        ktile<4, true, true>(T,     A, B, bm, bn, smem, tid, aBase, bBase, aS0, aS1, bE, bO, acc);
        ktile<4, true, true>(T + 1, A, B, bm, bn, smem, tid, aBase, bBase, aS0, aS1, bO, bE, acc);
    }
    ktile<4,  true,  true >(28, A, B, bm, bn, smem, tid, aBase, bBase, aS0, aS1, bE, bO, acc);
    ktile<4,  false, true >(29, A, B, bm, bn, smem, tid, aBase, bBase, aS0, aS1, bO, bE, acc);
    ktile<0,  false, true >(30, A, B, bm, bn, smem, tid, aBase, bBase, aS0, aS1, bE, bO, acc);
    ktile<-1, false, false>(31, A, B, bm, bn, smem, tid, aBase, bBase, aS0, aS1, bO, bE, acc);

    // ---- epilogue: out = s_row[row]*acc + bias[col]; LDS repack -> dwordx4 ----
    const int EST = 272;                       // row stride bytes (anti-conflict pad)
    char* eb = smem + wid * (16 * EST);        // 4352 B per wave
    const int C0 = bn + wn * 64;
    const int R0 = bm + wm * 128;
    const int rowsub = (lane >> 4) * 4;
    float bv[4];
    #pragma unroll
    for (int n = 0; n < 4; ++n) bv[n] = bias[C0 + n * 16 + lr];

    #pragma unroll
    for (int m = 0; m < 8; ++m) {
        float sr[4];
        #pragma unroll
        for (int i = 0; i < 4; ++i) sr[i] = s_row[R0 + m * 16 + rowsub + i];
        #pragma unroll
        for (int n = 0; n < 4; ++n)
            #pragma unroll
            for (int i = 0; i < 4; ++i)
                *reinterpret_cast<float*>(eb + (rowsub + i) * EST + (n * 16 + lr) * 4)
                    = (float)acc[m][n][i] * sr[i] + bv[n];
        #pragma unroll
        for (int q = 0; q < 4; ++q) {
            const int row = (lane >> 4) + q * 4;
            f32x4 v = *reinterpret_cast<const f32x4*>(eb + row * EST + lr * 16);
            *reinterpret_cast<f32x4*>(&C[(size_t)(R0 + m * 16 + row) * D_OUT + C0 + lr * 4]) = v;
        }
    }
}

// ---------------------------------------------------------------------------
extern "C" void kernel_launch(void* const* d_in, const int* in_sizes, int n_in,
                              void* d_out, int out_size, void* d_ws, size_t ws_size,
                              hipStream_t stream) {
    const float* x     = (const float*)d_in[0];   // [4,2048,2048]
    const float* w     = (const float*)d_in[1];   // [2048,2048]
    const float* bias  = (const float*)d_in[2];   // [2048]
    const float* gamma = (const float*)d_in[3];   // [2048]
    const float* beta  = (const float*)d_in[4];   // [2048]
    float* out = (float*)d_out;

    char* ws = (char*)d_ws;
    double* partials = (double*)ws;                         // 8KB
    float*  s_row    = (float*)(ws + 8192);                 // 32KB (8192 rows)
    char*   wq       = ws + 65536;                          // 4MB  i8 [N][K]
    char*   xn       = ws + 65536 + 4ull * 1024 * 1024;     // 16MB i8 [M][K]

    hipFuncSetAttribute(reinterpret_cast<const void*>(gemm256_kernel),
                        hipFuncAttributeMaxDynamicSharedMemorySize, 131072);

    absum_kernel   <<<1024, 256, 0, stream>>>(w, partials);
    quant_kernel   <<<4096, 256, 0, stream>>>(w, partials, wq);
    ln_kernel      <<<M_TOTAL, 256, 0, stream>>>(x, gamma, beta, xn, s_row);
    gemm256_kernel <<<dim3(D_OUT / BN, M_TOTAL / BM), 512, 131072, stream>>>(xn, wq, bias, s_row, out);
}

// Round 9
// 68.337 us; speedup vs baseline: 1.3890x; 1.0243x over previous
//
#include <hip/hip_runtime.h>
#include <hip/hip_bf16.h>

#define D_IN  2048
#define D_OUT 2048
#define M_TOTAL 8192   // B*S = 4*2048

typedef __attribute__((ext_vector_type(4))) int   i32x4;   // i8 MFMA A/B/C frags
typedef __attribute__((ext_vector_type(4))) float f32x4;

typedef const __attribute__((address_space(1))) void gvoid_t;
typedef __attribute__((address_space(3))) void lvoid_t;

// ---------------------------------------------------------------------------
// Kernel 1: per-block partial sums of |w| in fp64 (deterministic, no atomics)
// ---------------------------------------------------------------------------
__global__ __launch_bounds__(256) void absum_kernel(const float* __restrict__ w,
                                                    double* __restrict__ partials) {
    const int n4 = (D_OUT * D_IN) / 4;          // 1,048,576 float4s
    int tid = blockIdx.x * 256 + threadIdx.x;
    int stride = gridDim.x * 256;
    double s = 0.0;
    for (int i = tid; i < n4; i += stride) {
        float4 v = reinterpret_cast<const float4*>(w)[i];
        s += (double)fabsf(v.x) + (double)fabsf(v.y) +
             (double)fabsf(v.z) + (double)fabsf(v.w);
    }
    for (int off = 32; off; off >>= 1) s += __shfl_xor(s, off, 64);
    __shared__ double ls[4];
    if ((threadIdx.x & 63) == 0) ls[threadIdx.x >> 6] = s;
    __syncthreads();
    if (threadIdx.x == 0)
        partials[blockIdx.x] = ls[0] + ls[1] + ls[2] + ls[3];
}

// ---------------------------------------------------------------------------
// Kernel 2 (merged): blocks 0..4095 = ternary quantize w -> int8 [N][K];
// blocks 4096..12287 = LayerNorm -> int8 [M][K] + per-row scale.
// (quant's 16MB read overlaps LN's streams in one dispatch; one less launch)
// ---------------------------------------------------------------------------
__device__ __forceinline__ unsigned pk4(float a, float b, float c, float d, float is) {
    int q0 = (int)rintf(a * is); q0 = min(127, max(-127, q0));
    int q1 = (int)rintf(b * is); q1 = min(127, max(-127, q1));
    int q2 = (int)rintf(c * is); q2 = min(127, max(-127, q2));
    int q3 = (int)rintf(d * is); q3 = min(127, max(-127, q3));
    return  (unsigned)(unsigned char)(char)q0        |
           ((unsigned)(unsigned char)(char)q1 << 8)  |
           ((unsigned)(unsigned char)(char)q2 << 16) |
           ((unsigned)(unsigned char)(char)q3 << 24);
}

__global__ __launch_bounds__(256) void quantln_kernel(const float* __restrict__ w,
                                                      const double* __restrict__ partials,
                                                      char* __restrict__ wq,
                                                      const float* __restrict__ x,
                                                      const float* __restrict__ gamma,
                                                      const float* __restrict__ beta,
                                                      char* __restrict__ xn,
                                                      float* __restrict__ s_row) {
    int t = threadIdx.x;
    if (blockIdx.x < 4096) {
        // ---- ternary quantize (finalize folded in, deterministic) ----
        double s = partials[t] + partials[t + 256] + partials[t + 512] + partials[t + 768];
        for (int off = 32; off; off >>= 1) s += __shfl_xor(s, off, 64);
        __shared__ double ls[4];
        if ((t & 63) == 0) ls[t >> 6] = s;
        __syncthreads();
        double tot = ls[0] + ls[1] + ls[2] + ls[3];
        double inv = 1.0 / (tot / 4194304.0 + 1e-5);

        int i = blockIdx.x * 256 + t;
        float4 v = reinterpret_cast<const float4*>(w)[i];
        unsigned o = 0;
        #pragma unroll
        for (int j = 0; j < 4; ++j) {
            float wf = (j == 0) ? v.x : (j == 1) ? v.y : (j == 2) ? v.z : v.w;
            double r = rint((double)wf * inv);
            r = fmin(1.0, fmax(-1.0, r));
            int q = (int)r;
            o |= ((unsigned)(unsigned char)(char)q) << (8 * j);
        }
        reinterpret_cast<unsigned*>(wq)[i] = o;
    } else {
        // ---- LayerNorm -> int8 + row scale ----
        int row = blockIdx.x - 4096;
        const float4* xr = reinterpret_cast<const float4*>(x + (size_t)row * D_IN);
        float4 v0 = xr[t];
        float4 v1 = xr[t + 256];
        float s  = v0.x + v0.y + v0.z + v0.w + v1.x + v1.y + v1.z + v1.w;
        float sq = v0.x*v0.x + v0.y*v0.y + v0.z*v0.z + v0.w*v0.w
                 + v1.x*v1.x + v1.y*v1.y + v1.z*v1.z + v1.w*v1.w;
        for (int off = 32; off; off >>= 1) {
            s  += __shfl_xor(s,  off, 64);
            sq += __shfl_xor(sq, off, 64);
        }
        __shared__ float lss[4], lqq[4], lmx[4];
        if ((t & 63) == 0) { lss[t >> 6] = s; lqq[t >> 6] = sq; }
        __syncthreads();
        s  = lss[0] + lss[1] + lss[2] + lss[3];
        sq = lqq[0] + lqq[1] + lqq[2] + lqq[3];
        float mu  = s * (1.0f / D_IN);
        float var = sq * (1.0f / D_IN) - mu * mu;
        float inv = rsqrtf(var + 1e-5f);

        const float4* g4 = reinterpret_cast<const float4*>(gamma);
        const float4* b4 = reinterpret_cast<const float4*>(beta);
        float4 g0 = g4[t], g1 = g4[t + 256];
        float4 b0 = b4[t], b1 = b4[t + 256];

        float a0 = (v0.x - mu) * inv * g0.x + b0.x;
        float a1 = (v0.y - mu) * inv * g0.y + b0.y;
        float a2 = (v0.z - mu) * inv * g0.z + b0.z;
        float a3 = (v0.w - mu) * inv * g0.w + b0.w;
        float a4 = (v1.x - mu) * inv * g1.x + b1.x;
        float a5 = (v1.y - mu) * inv * g1.y + b1.y;
        float a6 = (v1.z - mu) * inv * g1.z + b1.z;
        float a7 = (v1.w - mu) * inv * g1.w + b1.w;

        float mx = fmaxf(fmaxf(fmaxf(fabsf(a0), fabsf(a1)), fmaxf(fabsf(a2), fabsf(a3))),
                         fmaxf(fmaxf(fabsf(a4), fabsf(a5)), fmaxf(fabsf(a6), fabsf(a7))));
        for (int off = 32; off; off >>= 1) mx = fmaxf(mx, __shfl_xor(mx, off, 64));
        if ((t & 63) == 0) lmx[t >> 6] = mx;
        __syncthreads();
        float rowmax = fmaxf(fmaxf(lmx[0], lmx[1]), fmaxf(lmx[2], lmx[3]));

        float is = (rowmax > 0.0f) ? (127.0f / rowmax) : 0.0f;
        char* orow = xn + (size_t)row * D_IN;
        reinterpret_cast<unsigned*>(orow)[t]        = pk4(a0, a1, a2, a3, is);
        reinterpret_cast<unsigned*>(orow + 1024)[t] = pk4(a4, a5, a6, a7, is);
        if (t == 0) s_row[row] = rowmax * (1.0f / 127.0f);
    }
}

// ---------------------------------------------------------------------------
// Kernel 3: 256x128-tile 4-wave INT8 MFMA GEMM, 2 BLOCKS/CU.
// R8 change: occupancy-2 structure. Each SIMD hosts 2 waves from DIFFERENT
// blocks (independent barrier groups) -> when one block drains vmcnt/barrier,
// the other block's waves feed the matrix pipe (m114 cross-wave overlap).
// Attacks the measured zero-overlap (tile time ~= serial sum of MFMA 1280cy
// + LDS 768cy + VMEM 585cy per SIMD).
// LDS 48KB/block: 2 slots x 24KB (A 16KB @ s*24K, B 8KB @ s*24K+16K).
// Per K-tile: ph0 {read A m0-3 + B (8 b128) | stage A(T+1)->so (4 gload) |
//   16 MFMA | barrier}; ph1 {read A m4-7 (4) | stage B(T+1)->so+16K (2) |
//   16 MFMA | vmcnt(0) | barrier}.
// Ledger: WAR: so's last reads lgkm-complete before T-1.ph1 cluster < its
//   barrier < T.ph0 stage. RAW: T+1.ph0 reads so after T.ph1 vmcnt(0)+barrier.
// Bank swizzle: R7-proven geometry (f(row)=(row>>1)&3), both sides.
// ---------------------------------------------------------------------------
#define NT (D_IN / 64)         // 32 K-tiles
#define SLOT2 24576

__device__ __forceinline__ void stageA(const char* __restrict__ gbase,
                                       int grow0, int kcol0,
                                       char* smem, int ldsbase, int tid) {
    const int lane = tid & 63;
    const int w    = tid >> 6;              // 0..3
    const int colx = (((lane & 3) ^ ((lane >> 3) & 3)) << 4);
    #pragma unroll
    for (int j = 0; j < 4; ++j) {
        const int c = j * 4 + w;            // 16 chunks (256 rows)
        const int r = c * 16 + (lane >> 2);
        const char* g = gbase + (size_t)(grow0 + r) * D_IN + kcol0 + colx;
        char* l = smem + ldsbase + c * 1024 + lane * 16;
        __builtin_amdgcn_global_load_lds((gvoid_t*)g, (lvoid_t*)l, 16, 0, 0);
    }
}

__device__ __forceinline__ void stageB(const char* __restrict__ gbase,
                                       int grow0, int kcol0,
                                       char* smem, int ldsbase, int tid) {
    const int lane = tid & 63;
    const int w    = tid >> 6;
    const int colx = (((lane & 3) ^ ((lane >> 3) & 3)) << 4);
    #pragma unroll
    for (int j = 0; j < 2; ++j) {
        const int c = j * 4 + w;            // 8 chunks (128 rows)
        const int r = c * 16 + (lane >> 2);
        const char* g = gbase + (size_t)(grow0 + r) * D_IN + kcol0 + colx;
        char* l = smem + ldsbase + c * 1024 + lane * 16;
        __builtin_amdgcn_global_load_lds((gvoid_t*)g, (lvoid_t*)l, 16, 0, 0);
    }
}

__device__ __forceinline__ i32x4 rdfrag(const char* smem, int off) {
    return *reinterpret_cast<const i32x4*>(smem + off);
}

template<int W>
__device__ __forceinline__ void vm_wait() {
    if constexpr (W == 0) {
        asm volatile("s_waitcnt vmcnt(0)" ::: "memory");
        __builtin_amdgcn_sched_barrier(0);
    }
    // W == -1: no wait
}

#define MFMA16(ROW, AV, BV)                                                     \
    __builtin_amdgcn_sched_barrier(0);                                          \
    __builtin_amdgcn_s_setprio(1);                                              \
    _Pragma("unroll")                                                           \
    for (int m_ = 0; m_ < 4; ++m_)                                              \
        _Pragma("unroll")                                                       \
        for (int n_ = 0; n_ < 4; ++n_)                                          \
            acc[ROW + m_][n_] = __builtin_amdgcn_mfma_i32_16x16x64_i8(          \
                AV[m_], BV[n_], acc[ROW + m_][n_], 0, 0, 0);                    \
    __builtin_amdgcn_s_setprio(0);                                              \
    __builtin_amdgcn_sched_barrier(0);

template<bool S, int W>
__device__ __forceinline__ void ktile(int T,
        const char* __restrict__ A, const char* __restrict__ B,
        int bm, int bn, char* smem, int tid, int aBase, int bBase,
        i32x4 (&acc)[8][4]) {
    const int sb = (T & 1) * SLOT2;
    const int so = sb ^ SLOT2;

    // ---- ph0 ----
    i32x4 a0[4], b0[4], a1[4];
    #pragma unroll
    for (int f = 0; f < 4; ++f) a0[f] = rdfrag(smem, sb + aBase + f * 1024);
    #pragma unroll
    for (int f = 0; f < 4; ++f) b0[f] = rdfrag(smem, sb + 16384 + bBase + f * 1024);
    if (S) stageA(A, bm, (T + 1) * 64, smem, so, tid);
    MFMA16(0, a0, b0)
    __builtin_amdgcn_s_barrier();

    // ---- ph1 ----
    #pragma unroll
    for (int f = 0; f < 4; ++f) a1[f] = rdfrag(smem, sb + aBase + 4096 + f * 1024);
    if (S) stageB(B, bn, (T + 1) * 64, smem, so + 16384, tid);
    MFMA16(4, a1, b0)
    vm_wait<W>();
    __builtin_amdgcn_s_barrier();
}

__global__ __launch_bounds__(256, 2) void gemm128_kernel(const char* __restrict__ A,
                                                         const char* __restrict__ B,
                                                         const float* __restrict__ bias,
                                                         const float* __restrict__ s_row,
                                                         float* __restrict__ C) {
    __shared__ char smem[2 * SLOT2];       // 48 KB -> 2 blocks/CU
    const int tid  = threadIdx.x;
    const int lane = tid & 63;
    const int wid  = tid >> 6;             // 0..3
    const int wm   = wid >> 1;             // 0..1 (128-row half)
    const int wn   = wid & 1;              // 0..1 (64-col half)

    // XCD swizzle (grid=512, 512%8==0): XCD x owns swz x*64..x*64+63 ->
    // 4 consecutive bm panels (2MB A, L2-resident) x all 16 bn
    const int orig = blockIdx.y * gridDim.x + blockIdx.x;   // 0..511
    const int swz  = (orig & 7) * 64 + (orig >> 3);
    const int bm   = (swz >> 4) * 256;
    const int bn   = (swz & 15) * 128;

    const int lr   = lane & 15;
    const int rdbase = lr * 64 + ((((lane >> 4) ^ ((lr >> 1) & 3))) << 4);
    const int aBase = wm * 8192 + rdbase;   // wm*128 rows * 64B
    const int bBase = wn * 4096 + rdbase;   // wn*64 rows * 64B

    i32x4 acc[8][4];
    #pragma unroll
    for (int m = 0; m < 8; ++m)
        #pragma unroll
        for (int n = 0; n < 4; ++n)
            acc[m][n] = (i32x4){0, 0, 0, 0};

    // prologue: stage tile0 into slot0; drain; barrier
    stageA(A, bm, 0, smem, 0,     tid);
    stageB(B, bn, 0, smem, 16384, tid);
    asm volatile("s_waitcnt vmcnt(0)" ::: "memory");
    __builtin_amdgcn_sched_barrier(0);
    __builtin_amdgcn_s_barrier();

    for (int T = 0; T < NT - 1; ++T)
        ktile<true, 0>(T, A, B, bm, bn, smem, tid, aBase, bBase, acc);
    ktile<false, -1>(NT - 1, A, B, bm, bn, smem, tid, aBase, bBase, acc);

    // ---- epilogue: out = s_row[row]*acc + bias[col]; LDS repack -> dwordx4 ----
    // Last tile reads slot1 (24576+); eb uses slot0 region, per-wave private.
    const int EST = 272;
    char* eb = smem + wid * (16 * EST);    // 4 waves x 4352B = 17KB < 24KB
    const int C0 = bn + wn * 64;
    const int R0 = bm + wm * 128;
    const int rowsub = (lane >> 4) * 4;
    float bv[4];
    #pragma unroll
    for (int n = 0; n < 4; ++n) bv[n] = bias[C0 + n * 16 + lr];

    #pragma unroll
    for (int m = 0; m < 8; ++m) {
        float sr[4];
        #pragma unroll
        for (int i = 0; i < 4; ++i) sr[i] = s_row[R0 + m * 16 + rowsub + i];
        #pragma unroll
        for (int n = 0; n < 4; ++n)
            #pragma unroll
            for (int i = 0; i < 4; ++i)
                *reinterpret_cast<float*>(eb + (rowsub + i) * EST + (n * 16 + lr) * 4)
                    = (float)acc[m][n][i] * sr[i] + bv[n];
        #pragma unroll
        for (int q = 0; q < 4; ++q) {
            const int row = (lane >> 4) + q * 4;
            f32x4 v = *reinterpret_cast<const f32x4*>(eb + row * EST + lr * 16);
            *reinterpret_cast<f32x4*>(&C[(size_t)(R0 + m * 16 + row) * D_OUT + C0 + lr * 4]) = v;
        }
    }
}

// ---------------------------------------------------------------------------
extern "C" void kernel_launch(void* const* d_in, const int* in_sizes, int n_in,
                              void* d_out, int out_size, void* d_ws, size_t ws_size,
                              hipStream_t stream) {
    const float* x     = (const float*)d_in[0];   // [4,2048,2048]
    const float* w     = (const float*)d_in[1];   // [2048,2048]
    const float* bias  = (const float*)d_in[2];   // [2048]
    const float* gamma = (const float*)d_in[3];   // [2048]
    const float* beta  = (const float*)d_in[4];   // [2048]
    float* out = (float*)d_out;

    char* ws = (char*)d_ws;
    double* partials = (double*)ws;                         // 8KB
    float*  s_row    = (float*)(ws + 8192);                 // 32KB (8192 rows)
    char*   wq       = ws + 65536;                          // 4MB  i8 [N][K]
    char*   xn       = ws + 65536 + 4ull * 1024 * 1024;     // 16MB i8 [M][K]

    absum_kernel   <<<1024, 256, 0, stream>>>(w, partials);
    quantln_kernel <<<12288, 256, 0, stream>>>(w, partials, wq, x, gamma, beta, xn, s_row);
    gemm128_kernel <<<dim3(16, 32), 256, 0, stream>>>(xn, wq, bias, s_row, out);
}